// Round 1
// 336.388 us; speedup vs baseline: 1.0170x; 1.0170x over previous
//
#include <hip/hip_runtime.h>
#include <math.h>

#define NUM_GRAPHS 1024
#define IN_F 256
#define HID 512

typedef __bf16 bf16x4 __attribute__((ext_vector_type(4)));
typedef __bf16 bf16x8 __attribute__((ext_vector_type(8)));
typedef float  f32x4  __attribute__((ext_vector_type(4)));

// Wave-cooperative lower_bound: 64 probes/round, 3 rounds for N=200000.
// Sorted input => pred is a lane-prefix; popc(ballot) locates the bracket.
__device__ __forceinline__ int wave_lower_bound(const int* __restrict__ b, int n, int v, int lane) {
    int lo = 0, hi = n;
    while (lo < hi) {
        int stride = (hi - lo + 63) >> 6;
        int idx = lo + lane * stride;
        bool pred = (idx < hi) && (b[idx] < v);
        unsigned long long bal = __ballot(pred);
        int cnt = __popcll(bal);
        int nhi = lo + cnt * stride;
        lo = (cnt == 0) ? lo : lo + (cnt - 1) * stride + 1;
        hi = (nhi < hi) ? nhi : hi;
    }
    return lo;
}

__device__ __forceinline__ float bdot8(bf16x8 a, float4 w0, float4 w1) {
    return (float)a[0]*w0.x + (float)a[1]*w0.y + (float)a[2]*w0.z + (float)a[3]*w0.w
         + (float)a[4]*w1.x + (float)a[5]*w1.y + (float)a[6]*w1.z + (float)a[7]*w1.w;
}

// ---------------- L1: pooling (blocks 0..1023) + W transposes (blocks 1024..1151) ----------------
__global__ __launch_bounds__(256) void pool_prep_kernel(
    const float* __restrict__ x, const int* __restrict__ batch, int N,
    __bf16* __restrict__ pool_mean, __bf16* __restrict__ pool_max,
    __bf16* __restrict__ pool_sum,
    const float* __restrict__ Wm, const float* __restrict__ Wx, const float* __restrict__ Wsm,
    const float* __restrict__ Wout,
    __bf16* __restrict__ wt,      // 3 x [512][256]
    __bf16* __restrict__ wtout)   // [256][512]
{
    if (blockIdx.x >= NUM_GRAPHS) {
        // ---- transpose role ----
        __shared__ float tile[64][65];
        int tb = blockIdx.x - NUM_GRAPHS;     // 0..127
        int z = tb >> 5, t = tb & 31;
        const float* S; __bf16* D; int SC, SR, r0, cb;
        if (z < 3) {
            S = (z==0) ? Wm : (z==1) ? Wx : Wsm;
            D = wt + (size_t)z * HID * IN_F;
            SR = 256; SC = 512;
            r0 = (t >> 3) * 64; cb = (t & 7) * 64;
        } else {
            S = Wout; D = wtout;
            SR = 512; SC = 256;
            r0 = (t >> 2) * 64; cb = (t & 3) * 64;
        }
        int r  = threadIdx.x >> 2;
        int c0 = (threadIdx.x & 3) * 16;
        #pragma unroll
        for (int j = 0; j < 4; ++j) {
            float4 v = *(const float4*)&S[(size_t)(r0 + r)*SC + cb + c0 + j*4];
            tile[r][c0+j*4+0] = v.x; tile[r][c0+j*4+1] = v.y;
            tile[r][c0+j*4+2] = v.z; tile[r][c0+j*4+3] = v.w;
        }
        __syncthreads();
        #pragma unroll
        for (int j = 0; j < 4; ++j) {
            bf16x4 o;
            o.x = (__bf16)tile[c0+j*4+0][r];
            o.y = (__bf16)tile[c0+j*4+1][r];
            o.z = (__bf16)tile[c0+j*4+2][r];
            o.w = (__bf16)tile[c0+j*4+3][r];
            *(bf16x4*)&D[(size_t)(cb + r)*SR + r0 + c0 + j*4] = o;
        }
        return;
    }
    // ---- pool role ----
    int g = blockIdx.x;
    int w = threadIdx.x >> 6, lane = threadIdx.x & 63;
    __shared__ int sb[2];
    if (w < 2) {                   // waves 0/1: parallel-probe search (3 rounds)
        int lb = wave_lower_bound(batch, N, g + w, lane);
        if (lane == 0) sb[w] = lb;
    }
    __syncthreads();
    int start = sb[0], end = sb[1];
    int cnt = end - start;
    const float4* x4 = (const float4*)x;
    float4 s = make_float4(0.f, 0.f, 0.f, 0.f);
    float4 m = make_float4(-INFINITY, -INFINITY, -INFINITY, -INFINITY);
    int r = start + w;
    for (; r + 12 < end; r += 16) {
        float4 v0 = x4[(size_t)(r     )*64 + lane];
        float4 v1 = x4[(size_t)(r +  4)*64 + lane];
        float4 v2 = x4[(size_t)(r +  8)*64 + lane];
        float4 v3 = x4[(size_t)(r + 12)*64 + lane];
        s.x += (v0.x+v1.x)+(v2.x+v3.x); s.y += (v0.y+v1.y)+(v2.y+v3.y);
        s.z += (v0.z+v1.z)+(v2.z+v3.z); s.w += (v0.w+v1.w)+(v2.w+v3.w);
        m.x = fmaxf(m.x, fmaxf(fmaxf(v0.x,v1.x), fmaxf(v2.x,v3.x)));
        m.y = fmaxf(m.y, fmaxf(fmaxf(v0.y,v1.y), fmaxf(v2.y,v3.y)));
        m.z = fmaxf(m.z, fmaxf(fmaxf(v0.z,v1.z), fmaxf(v2.z,v3.z)));
        m.w = fmaxf(m.w, fmaxf(fmaxf(v0.w,v1.w), fmaxf(v2.w,v3.w)));
    }
    for (; r < end; r += 4) {
        float4 v = x4[(size_t)r*64 + lane];
        s.x += v.x; s.y += v.y; s.z += v.z; s.w += v.w;
        m.x = fmaxf(m.x, v.x); m.y = fmaxf(m.y, v.y);
        m.z = fmaxf(m.z, v.z); m.w = fmaxf(m.w, v.w);
    }
    __shared__ float4 Ls[4][64];
    __shared__ float4 Lm[4][64];
    Ls[w][lane] = s; Lm[w][lane] = m;
    __syncthreads();
    if (w == 0) {
        float4 s0 = Ls[0][lane], s1 = Ls[1][lane], s2 = Ls[2][lane], s3 = Ls[3][lane];
        float4 m0 = Lm[0][lane], m1 = Lm[1][lane], m2 = Lm[2][lane], m3 = Lm[3][lane];
        float4 st, mt;
        st.x = (s0.x+s1.x)+(s2.x+s3.x); st.y = (s0.y+s1.y)+(s2.y+s3.y);
        st.z = (s0.z+s1.z)+(s2.z+s3.z); st.w = (s0.w+s1.w)+(s2.w+s3.w);
        mt.x = fmaxf(fmaxf(m0.x,m1.x), fmaxf(m2.x,m3.x));
        mt.y = fmaxf(fmaxf(m0.y,m1.y), fmaxf(m2.y,m3.y));
        mt.z = fmaxf(fmaxf(m0.z,m1.z), fmaxf(m2.z,m3.z));
        mt.w = fmaxf(fmaxf(m0.w,m1.w), fmaxf(m2.w,m3.w));
        float inv = 1.0f / fmaxf((float)cnt, 1.0f);
        if (cnt == 0) mt = make_float4(0.f, 0.f, 0.f, 0.f);
        bf16x4 sb4, mb4, xb4;
        sb4.x = (__bf16)st.x;       sb4.y = (__bf16)st.y;
        sb4.z = (__bf16)st.z;       sb4.w = (__bf16)st.w;
        mb4.x = (__bf16)(st.x*inv); mb4.y = (__bf16)(st.y*inv);
        mb4.z = (__bf16)(st.z*inv); mb4.w = (__bf16)(st.w*inv);
        xb4.x = (__bf16)mt.x;       xb4.y = (__bf16)mt.y;
        xb4.z = (__bf16)mt.z;       xb4.w = (__bf16)mt.w;
        size_t o = (size_t)g*64 + lane;
        ((bf16x4*)pool_sum)[o]  = sb4;
        ((bf16x4*)pool_mean)[o] = mb4;
        ((bf16x4*)pool_max)[o]  = xb4;
    }
}

// ---------------- L2: three transform GEMMs via bf16 MFMA, zero LDS, bf16 out ----------------
// 32x64 tiles, grid (8,32,3) = 768 blocks = exactly 3 blocks/CU (was 384 = 1.5/CU).
__global__ __launch_bounds__(256) void transform_mfma(
    const __bf16* __restrict__ pm, const __bf16* __restrict__ px, const __bf16* __restrict__ ps,
    const __bf16* __restrict__ wtm, const __bf16* __restrict__ wtx, const __bf16* __restrict__ wts,
    const float* __restrict__ bm_, const float* __restrict__ bx_, const float* __restrict__ bs_,
    __bf16* __restrict__ r_mean, __bf16* __restrict__ r_max, __bf16* __restrict__ r_sum)
{
    int z = blockIdx.z;
    const __bf16* A  = (z==0) ? pm  : (z==1) ? px  : ps;
    const __bf16* Bt = (z==0) ? wtm : (z==1) ? wtx : wts;
    const float* bias= (z==0) ? bm_ : (z==1) ? bx_ : bs_;
    __bf16* R        = (z==0) ? r_mean : (z==1) ? r_max : r_sum;

    int bn0 = blockIdx.x * 64;
    int bm0 = blockIdx.y * 32;
    int w = threadIdx.x >> 6, lane = threadIdx.x & 63;
    int wm = w & 1, wn = w >> 1;          // wave -> (M half, N half)
    int qm = lane >> 4, rm = lane & 15;
    const bf16x8* Arow = (const bf16x8*)(A + (size_t)(bm0 + wm*16 + rm)*IN_F);
    const bf16x8* B0 = (const bf16x8*)(Bt + (size_t)(bn0 + wn*32 +  0 + rm)*IN_F);
    const bf16x8* B1 = (const bf16x8*)(Bt + (size_t)(bn0 + wn*32 + 16 + rm)*IN_F);
    f32x4 a0 = {0.f,0.f,0.f,0.f}, a1 = a0;
    #pragma unroll
    for (int j = 0; j < 8; ++j) {
        int fi = j*4 + qm;
        bf16x8 af = Arow[fi];
        a0 = __builtin_amdgcn_mfma_f32_16x16x32_bf16(af, B0[fi], a0, 0, 0, 0);
        a1 = __builtin_amdgcn_mfma_f32_16x16x32_bf16(af, B1[fi], a1, 0, 0, 0);
    }
    int row0 = bm0 + wm*16 + qm*4;
    float b0 = bias[bn0 + wn*32 +  0 + rm];
    float b1 = bias[bn0 + wn*32 + 16 + rm];
    #pragma unroll
    for (int r = 0; r < 4; ++r) {
        __bf16* Rr = R + (size_t)(row0 + r)*HID;
        Rr[bn0 + wn*32 +  0 + rm] = (__bf16)(a0[r] + b0);
        Rr[bn0 + wn*32 + 16 + rm] = (__bf16)(a1[r] + b1);
    }
}

// ---------------- L3: gates + fusion + MFMA out-projection + layernorm ----------------
// EM 16 -> 8: 128 blocks (2x CU coverage), halved staging + serial-phase latency.
// MFMA M-tile stays 16; A rows 8..15 zero-filled, their outputs masked on store.
#define EM 8
__global__ __launch_bounds__(256) void fused_tail(
    const __bf16* __restrict__ r_mean, const __bf16* __restrict__ r_max, const __bf16* __restrict__ r_sum,
    const float* __restrict__ gwm, const float* __restrict__ gbm,
    const float* __restrict__ gwx, const float* __restrict__ gbx,
    const float* __restrict__ gws, const float* __restrict__ gbs,
    const __bf16* __restrict__ wtout, const float* __restrict__ bout,
    const float* __restrict__ gamma, const float* __restrict__ beta,
    float* __restrict__ out)
{
    int g0 = blockIdx.x * EM;
    int tid = threadIdx.x;
    int w = tid >> 6, lane = tid & 63;
    int qm = lane >> 4, rm = lane & 15;

    __shared__ __align__(16) char smem_raw[3*EM*HID*2];   // 24 KB: reprs, later Es
    __bf16 (*R3)[EM][HID] = (__bf16(*)[EM][HID])smem_raw; // R3[z][g][k]
    float (*Es)[264] = (float(*)[264])smem_raw;           // [8][264] f32 = 8.25 KB
    __shared__ __bf16 pooled[16][520];                    // rows 0..7 live, 8..15 zero
    __shared__ float wgt[EM][3];

    // stage reprs: 3*8*512 bf16 = 1536 bf16x8 chunks over 256 threads
    #pragma unroll
    for (int i = 0; i < 6; ++i) {
        int c = tid + i*256;
        int z = c >> 9, rem = c & 511;
        int g = rem >> 6, kc = (rem & 63) * 8;
        const __bf16* src = (z==0) ? r_mean : (z==1) ? r_max : r_sum;
        *(bf16x8*)&R3[z][g][kc] = *(const bf16x8*)&src[(size_t)(g0 + g)*HID + kc];
    }
    // zero pooled rows 8..15 (8*520 bf16 = 520 chunks)
    #pragma unroll
    for (int i = 0; i < 3; ++i) {
        int c = tid + i*256;
        if (c < 520) {
            bf16x8 zr = {};
            *(bf16x8*)&pooled[8 + c/65][(c%65)*8] = zr;
        }
    }
    __syncthreads();

    float4 wm0 = *(const float4*)&gwm[lane*8], wm1 = *(const float4*)&gwm[lane*8+4];
    float4 wx0 = *(const float4*)&gwx[lane*8], wx1 = *(const float4*)&gwx[lane*8+4];
    float4 ws0 = *(const float4*)&gws[lane*8], ws1 = *(const float4*)&gws[lane*8+4];
    #pragma unroll
    for (int gi = 0; gi < 2; ++gi) {
        int g = w*2 + gi;
        bf16x8 am = *(const bf16x8*)&R3[0][g][lane*8];
        bf16x8 ax = *(const bf16x8*)&R3[1][g][lane*8];
        bf16x8 as = *(const bf16x8*)&R3[2][g][lane*8];
        float dm  = bdot8(am, wm0, wm1);
        float dx  = bdot8(ax, wx0, wx1);
        float dsv = bdot8(as, ws0, ws1);
        #pragma unroll
        for (int off = 32; off > 0; off >>= 1) {
            dm  += __shfl_xor(dm,  off, 64);
            dx  += __shfl_xor(dx,  off, 64);
            dsv += __shfl_xor(dsv, off, 64);
        }
        if (lane == 0) {
            float sm = 1.f/(1.f + expf(-(dm  + gbm[0])));
            float sx = 1.f/(1.f + expf(-(dx  + gbx[0])));
            float ss = 1.f/(1.f + expf(-(dsv + gbs[0])));
            float em = expf(sm), ex = expf(sx), es = expf(ss);
            float inv = 1.f/(em + ex + es);
            wgt[g][0] = em*inv; wgt[g][1] = ex*inv; wgt[g][2] = es*inv;
        }
    }
    __syncthreads();

    // gated fusion: 8*512/8 = 512 chunks over 256 threads
    #pragma unroll
    for (int i = 0; i < 2; ++i) {
        int c = tid + i*256;
        int g = c >> 6, kc = (c & 63) * 8;
        bf16x8 am = *(const bf16x8*)&R3[0][g][kc];
        bf16x8 ax = *(const bf16x8*)&R3[1][g][kc];
        bf16x8 as = *(const bf16x8*)&R3[2][g][kc];
        float w0 = wgt[g][0], w1 = wgt[g][1], w2 = wgt[g][2];
        bf16x8 o;
        #pragma unroll
        for (int e = 0; e < 8; ++e)
            o[e] = (__bf16)(w0*(float)am[e] + w1*(float)ax[e] + w2*(float)as[e]);
        *(bf16x8*)&pooled[g][kc] = o;
    }
    __syncthreads();

    f32x4 ac0 = {0.f,0.f,0.f,0.f}, ac1 = ac0, ac2 = ac0, ac3 = ac0;
    const __bf16* Bt0 = wtout + (size_t)((w*4+0)*16 + rm)*HID;
    const __bf16* Bt1 = wtout + (size_t)((w*4+1)*16 + rm)*HID;
    const __bf16* Bt2 = wtout + (size_t)((w*4+2)*16 + rm)*HID;
    const __bf16* Bt3 = wtout + (size_t)((w*4+3)*16 + rm)*HID;
    #pragma unroll
    for (int kk = 0; kk < 16; ++kk) {
        int ko = kk*32 + qm*8;
        bf16x8 af = *(const bf16x8*)&pooled[rm][ko];
        ac0 = __builtin_amdgcn_mfma_f32_16x16x32_bf16(af, *(const bf16x8*)&Bt0[ko], ac0, 0, 0, 0);
        ac1 = __builtin_amdgcn_mfma_f32_16x16x32_bf16(af, *(const bf16x8*)&Bt1[ko], ac1, 0, 0, 0);
        ac2 = __builtin_amdgcn_mfma_f32_16x16x32_bf16(af, *(const bf16x8*)&Bt2[ko], ac2, 0, 0, 0);
        ac3 = __builtin_amdgcn_mfma_f32_16x16x32_bf16(af, *(const bf16x8*)&Bt3[ko], ac3, 0, 0, 0);
    }
    __syncthreads();   // R3 dead -> alias as Es

    float bo0 = bout[(w*4+0)*16 + rm], bo1 = bout[(w*4+1)*16 + rm];
    float bo2 = bout[(w*4+2)*16 + rm], bo3 = bout[(w*4+3)*16 + rm];
    if (qm < 2) {      // output rows 0..7 only (rows 8..15 are the zero-pad half)
        #pragma unroll
        for (int r = 0; r < 4; ++r) {
            int g = qm*4 + r;
            Es[g][(w*4+0)*16 + rm] = ac0[r] + bo0;
            Es[g][(w*4+1)*16 + rm] = ac1[r] + bo1;
            Es[g][(w*4+2)*16 + rm] = ac2[r] + bo2;
            Es[g][(w*4+3)*16 + rm] = ac3[r] + bo3;
        }
    }
    __syncthreads();

    float4 ga = *(const float4*)&gamma[lane*4];
    float4 be = *(const float4*)&beta[lane*4];
    #pragma unroll
    for (int i = 0; i < 2; ++i) {
        int g = w*2 + i;
        float4 v = *(const float4*)&Es[g][lane*4];
        float s  = (v.x + v.y) + (v.z + v.w);
        float sq = (v.x*v.x + v.y*v.y) + (v.z*v.z + v.w*v.w);
        #pragma unroll
        for (int off = 32; off > 0; off >>= 1) {
            s  += __shfl_xor(s,  off, 64);
            sq += __shfl_xor(sq, off, 64);
        }
        float mu  = s * (1.0f/IN_F);
        float var = sq * (1.0f/IN_F) - mu*mu;
        float rs  = rsqrtf(var + 1e-5f);
        float4 o;
        o.x = (v.x - mu)*rs*ga.x + be.x;
        o.y = (v.y - mu)*rs*ga.y + be.y;
        o.z = (v.z - mu)*rs*ga.z + be.z;
        o.w = (v.w - mu)*rs*ga.w + be.w;
        *(float4*)&out[(size_t)(g0 + g)*IN_F + lane*4] = o;
    }
}

extern "C" void kernel_launch(void* const* d_in, const int* in_sizes, int n_in,
                              void* d_out, int out_size, void* d_ws, size_t ws_size,
                              hipStream_t stream)
{
    const float* x        = (const float*)d_in[0];
    const int*   batch    = (const int*)d_in[1];
    const float* W_mean   = (const float*)d_in[2];
    const float* b_mean   = (const float*)d_in[3];
    const float* W_max    = (const float*)d_in[4];
    const float* b_max    = (const float*)d_in[5];
    const float* W_sum    = (const float*)d_in[6];
    const float* b_sum    = (const float*)d_in[7];
    const float* g_mean_w = (const float*)d_in[8];
    const float* g_mean_b = (const float*)d_in[9];
    const float* g_max_w  = (const float*)d_in[10];
    const float* g_max_b  = (const float*)d_in[11];
    const float* g_sum_w  = (const float*)d_in[12];
    const float* g_sum_b  = (const float*)d_in[13];
    const float* W_out    = (const float*)d_in[14];
    const float* b_out    = (const float*)d_in[15];
    const float* ln_gamma = (const float*)d_in[16];
    const float* ln_beta  = (const float*)d_in[17];
    float* out = (float*)d_out;
    int N = in_sizes[1];   // 200000 nodes

    // workspace layout (all bf16)
    __bf16* B = (__bf16*)d_ws;
    __bf16* pm    = B;                                   // [1024,256] x3
    __bf16* px    = pm  + (size_t)NUM_GRAPHS*IN_F;
    __bf16* psu   = px  + (size_t)NUM_GRAPHS*IN_F;
    __bf16* wtm   = psu + (size_t)NUM_GRAPHS*IN_F;       // [512,256] x3
    __bf16* wtx   = wtm + (size_t)HID*IN_F;
    __bf16* wts   = wtx + (size_t)HID*IN_F;
    __bf16* wtout = wts + (size_t)HID*IN_F;              // [256,512]
    __bf16* r_mean = wtout + (size_t)IN_F*HID;           // [1024,512] x3
    __bf16* r_max  = r_mean + (size_t)NUM_GRAPHS*HID;
    __bf16* r_sum  = r_max  + (size_t)NUM_GRAPHS*HID;

    pool_prep_kernel<<<NUM_GRAPHS + 128, 256, 0, stream>>>(
        x, batch, N, pm, px, psu,
        W_mean, W_max, W_sum, W_out, wtm, wtout);

    dim3 gridC(HID/64, NUM_GRAPHS/32, 3);   // (8,32,3) = 768 blocks = 3/CU
    transform_mfma<<<gridC, 256, 0, stream>>>(pm, px, psu, wtm, wtx, wts,
                                              b_mean, b_max, b_sum,
                                              r_mean, r_max, r_sum);

    fused_tail<<<NUM_GRAPHS/EM, 256, 0, stream>>>(r_mean, r_max, r_sum,
                                                  g_mean_w, g_mean_b, g_max_w, g_max_b,
                                                  g_sum_w, g_sum_b,
                                                  wtout, b_out, ln_gamma, ln_beta, out);
}